// Round 1
// baseline (624.577 us; speedup 1.0000x reference)
//
#include <hip/hip_runtime.h>
#include <math.h>

// Problem constants
#define BB   128
#define LL   512
#define CC   321
#define PREDD 336
// Seasonal MLP: rows = B*C*S = 164352, dims 128 -> 512 -> 128 (x2 blocks)

using bf16x8  = __attribute__((ext_vector_type(8))) __bf16;
using floatx4 = __attribute__((ext_vector_type(4))) float;
using uintx4  = __attribute__((ext_vector_type(4))) unsigned int;
typedef unsigned short u16;

__device__ __forceinline__ u16 f2bf(float f){
    union { float f; unsigned u; } v; v.f = f;
    unsigned r = v.u + 0x7FFFu + ((v.u >> 16) & 1u);   // RNE
    return (u16)(r >> 16);
}

// ---------------- weight prep: fp32 -> bf16, pre-transposed [Ncols][K] ----------------
__global__ void prep_k(const float* __restrict__ W11, const float* __restrict__ W12,
                       const float* __restrict__ W21, const float* __restrict__ W22,
                       const float* __restrict__ Wtr, const float* __restrict__ Wse,
                       u16* __restrict__ BT1, u16* __restrict__ BT2,
                       u16* __restrict__ BT3, u16* __restrict__ BT4,
                       u16* __restrict__ BT5)
{
    int idx = blockIdx.x * 256 + threadIdx.x;
    if (idx < 65536){
        int h = idx >> 7, k = idx & 127;          // BT1/BT3: [512][128] = W11^T / W21^T
        BT1[idx] = f2bf(W11[k*512 + h]);
        BT3[idx] = f2bf(W21[k*512 + h]);
        int n = idx >> 9, k2 = idx & 511;         // BT2/BT4: [128][512] = W12^T / W22^T
        BT2[idx] = f2bf(W12[k2*128 + n]);
        BT4[idx] = f2bf(W22[k2*128 + n]);
    }
    if (idx < 393216){
        // BT5: [384][1024]; k<512 -> W_tr rows; k>=512 -> W_se rows permuted to (s,n)-major
        int p = idx >> 10, k = idx & 1023;
        float v = 0.f;
        if (p < PREDD){
            if (k < 512) v = Wtr[k*PREDD + p];
            else { int kk = k - 512; int s = kk >> 7; int n = kk & 127; v = Wse[(4*n + s)*PREDD + p]; }
        }
        BT5[idx] = f2bf(v);
    }
}

// ---------------- fused RevIN stats + moving-avg decomposition ----------------
// grid: B * ceil(C/16) blocks of 256. Per block: 16 channels, all 512 timesteps in LDS.
// Moving-average commutes with the RevIN affine, so we decompose raw x:
//   trend = (avg25(x) - m)*istd*w + b ;  seasonal = (x - avg25(x))*istd*w
__global__ __launch_bounds__(256) void decomp_k(
    const float* __restrict__ x, const float* __restrict__ rw, const float* __restrict__ rb,
    u16* __restrict__ Afin, u16* __restrict__ xs, float2* __restrict__ stats)
{
    __shared__ float xt[LL*16];
    __shared__ float red[2][16][16];
    __shared__ float sh_m[16], sh_istd[16];
    int b = blockIdx.x / 21, ct = blockIdx.x % 21;
    int tid = threadIdx.x;
    int cl = tid & 15, lp = tid >> 4;            // channel-in-tile, t-partition (0..15)
    int c = ct*16 + cl;
    bool valid = c < CC;
    const float* xb = x + (size_t)b*LL*CC;
    float s = 0.f, q = 0.f;
    for (int i = 0; i < 32; ++i){                // coalesced: 16 consecutive c per half-wave
        int t = lp + 16*i;
        float v = valid ? xb[(size_t)t*CC + c] : 0.f;
        xt[t*16 + cl] = v;
        s += v; q += v*v;
    }
    red[0][lp][cl] = s; red[1][lp][cl] = q;
    __syncthreads();
    if (tid < 16){
        float ss = 0.f, qq = 0.f;
        for (int j = 0; j < 16; ++j){ ss += red[0][j][tid]; qq += red[1][j][tid]; }
        float m  = ss * (1.f/512.f);
        float var = qq * (1.f/512.f) - m*m;
        float sd = sqrtf(var + 1e-5f);
        sh_m[tid] = m; sh_istd[tid] = 1.f/sd;
        int cc = ct*16 + tid;
        if (cc < CC) stats[(size_t)b*CC + cc] = make_float2(m, sd);
    }
    __syncthreads();
    if (!valid) return;
    float m = sh_m[cl], istd = sh_istd[cl];
    float w = rw[c] * istd, bbv = rb[c];
    size_t bc = (size_t)b*CC + c;
    u16* tr  = Afin + bc*1024;                   // trend -> concat-A cols [0,512)
    u16* xsr = xs   + bc*512;                    // seasonal in split layout: row bc*4+s, col n
    int t0 = lp*32;
    float win = 0.f;                             // 25-tap replicate-clamped window sum
    for (int d = -12; d <= 12; ++d){
        int u = t0 + d; u = u < 0 ? 0 : (u > 511 ? 511 : u);
        win += xt[u*16 + cl];
    }
    for (int i = 0; i < 32; ++i){
        int t = t0 + i;
        float Ax = win * (1.f/25.f);
        float xv = xt[t*16 + cl];
        tr[t] = f2bf((Ax - m)*w + bbv);
        xsr[(t&3)*128 + (t>>2)] = f2bf((xv - Ax)*w);
        int uo = t - 12; uo = uo < 0 ? 0 : uo;   // slide window t -> t+1
        int un = t + 13; un = un > 511 ? 511 : un;
        win += xt[un*16 + cl] - xt[uo*16 + cl];
    }
}

// ---------------- bf16 MFMA GEMM, 128x128 tile, fused epilogues ----------------
enum { EPI_GELU = 0, EPI_BIAS = 1, EPI_SEA = 2, EPI_FINAL = 3 };

template<int EPI, int KDIM>
__global__ __launch_bounds__(256, 2) void gemm_k(
    const u16* __restrict__ A, const u16* __restrict__ BT,
    u16* __restrict__ Cb, float* __restrict__ Cf,
    const float* __restrict__ bias, const float* __restrict__ bias2,
    const float* __restrict__ rw, const float* __restrict__ rb,
    const float2* __restrict__ stats, int Ncols)
{
    __shared__ u16 lA[128*72];   // stride 72 bf16: 16B-aligned rows, conflict-free frag reads
    __shared__ u16 lB[128*72];
    const int tid = threadIdx.x;
    const int row0 = blockIdx.y * 128;
    const int col0 = blockIdx.x * 128;
    const int lane = tid & 63;
    const int wv = tid >> 6;
    const int wm = wv & 1, wn = wv >> 1;         // 2x2 wave grid, 64x64 per wave
    const int quad = lane >> 4, cl = lane & 15;

    floatx4 acc[16];
#pragma unroll
    for (int i = 0; i < 16; ++i) acc[i] = (floatx4){0.f,0.f,0.f,0.f};

    const int srow = tid >> 3, sseg = tid & 7;   // staging: 8 threads x 16B per row
    const u16* Ag = A  + (size_t)(row0 + srow)*KDIM + sseg*8;
    const u16* Bg = BT + (size_t)(col0 + srow)*KDIM + sseg*8;

    for (int k0 = 0; k0 < KDIM; k0 += 64){
#pragma unroll
        for (int p = 0; p < 4; ++p){
            uintx4 av = *(const uintx4*)(Ag + (size_t)p*32*KDIM + k0);
            uintx4 bv = *(const uintx4*)(Bg + (size_t)p*32*KDIM + k0);
            int r = p*32 + srow;
            *(uintx4*)(lA + r*72 + sseg*8) = av;
            *(uintx4*)(lB + r*72 + sseg*8) = bv;
        }
        __syncthreads();
#pragma unroll
        for (int kk = 0; kk < 2; ++kk){
            const int lk = kk*32 + quad*8;
            bf16x8 af[4], bfr[4];
#pragma unroll
            for (int mt = 0; mt < 4; ++mt) af[mt]  = *(const bf16x8*)(lA + (wm*64 + mt*16 + cl)*72 + lk);
#pragma unroll
            for (int nt = 0; nt < 4; ++nt) bfr[nt] = *(const bf16x8*)(lB + (wn*64 + nt*16 + cl)*72 + lk);
#pragma unroll
            for (int mt = 0; mt < 4; ++mt)
#pragma unroll
                for (int nt = 0; nt < 4; ++nt)
                    acc[mt*4+nt] = __builtin_amdgcn_mfma_f32_16x16x32_bf16(af[mt], bfr[nt], acc[mt*4+nt], 0, 0, 0);
        }
        __syncthreads();
    }

#pragma unroll
    for (int mt = 0; mt < 4; ++mt){
#pragma unroll
        for (int nt = 0; nt < 4; ++nt){
            floatx4 v = acc[mt*4+nt];
            int gc = col0 + wn*64 + nt*16 + cl;
#pragma unroll
            for (int i = 0; i < 4; ++i){
                int gr = row0 + wm*64 + mt*16 + quad*4 + i;
                float val = v[i];
                if (EPI == EPI_GELU){
                    val += bias[gc];
                    val = 0.5f*val*(1.f + erff(val*0.70710678118654752f));   // exact gelu
                    Cb[(size_t)gr*Ncols + gc] = f2bf(val);
                } else if (EPI == EPI_BIAS){
                    val += bias[gc];
                    Cb[(size_t)gr*Ncols + gc] = f2bf(val);
                } else if (EPI == EPI_SEA){
                    // h2 row (bc*4+s, n) -> concat-A[bc][512 + s*128 + n]
                    val += bias[gc];
                    Cb[(size_t)(gr>>2)*1024 + 512 + (size_t)(gr&3)*128 + gc] = f2bf(val);
                } else { // EPI_FINAL: biases + RevIN denorm + [B,PRED,C] transpose
                    if (gc < PREDD){
                        val += bias[gc] + bias2[gc];
                        int bv2 = gr / CC;
                        int c  = gr - bv2*CC;
                        val = (val - rb[c]) / (rw[c] + 1e-10f);
                        float2 st = stats[gr];
                        val = val*st.y + st.x;
                        Cf[(size_t)bv2*(PREDD*CC) + (size_t)gc*CC + c] = val;
                    }
                }
            }
        }
    }
}

extern "C" void kernel_launch(void* const* d_in, const int* in_sizes, int n_in,
                              void* d_out, int out_size, void* d_ws, size_t ws_size,
                              hipStream_t stream)
{
    const float* x   = (const float*)d_in[0];
    const float* rvw = (const float*)d_in[1];
    const float* rvb = (const float*)d_in[2];
    const float* W11 = (const float*)d_in[3];
    const float* b11 = (const float*)d_in[4];
    const float* W12 = (const float*)d_in[5];
    const float* b12 = (const float*)d_in[6];
    const float* W21 = (const float*)d_in[7];
    const float* b21 = (const float*)d_in[8];
    const float* W22 = (const float*)d_in[9];
    const float* b22 = (const float*)d_in[10];
    const float* Wtr = (const float*)d_in[11];
    const float* btr = (const float*)d_in[12];
    const float* Wse = (const float*)d_in[13];
    const float* bse = (const float*)d_in[14];
    float* out = (float*)d_out;

    // workspace layout (bytes), all offsets 256-aligned; total ~296 MB
    char* ws = (char*)d_ws;
    u16* BT1 = (u16*)(ws + 0);            //  512x128 bf16
    u16* BT2 = (u16*)(ws + 131072);       //  128x512
    u16* BT3 = (u16*)(ws + 262144);       //  512x128
    u16* BT4 = (u16*)(ws + 393216);       //  128x512
    u16* BT5 = (u16*)(ws + 524288);       //  384x1024
    float2* stats = (float2*)(ws + 1310720);      // 41088 x {mean,std}
    u16* Afin = (u16*)(ws + 1639424);     // concat-A [41088][1024]: trend | sea
    u16* xs   = (u16*)(ws + 85787648);    // [164352][128] split seasonal (reused as h1)
    u16* X    = (u16*)(ws + 127861760);   // [164352][512] MLP hidden
    u16* h1   = xs;

    hipLaunchKernelGGL(prep_k, dim3(1536), dim3(256), 0, stream,
                       W11, W12, W21, W22, Wtr, Wse, BT1, BT2, BT3, BT4, BT5);
    hipLaunchKernelGGL(decomp_k, dim3(128*21), dim3(256), 0, stream,
                       x, rvw, rvb, Afin, xs, stats);
    hipLaunchKernelGGL((gemm_k<EPI_GELU, 128>), dim3(4, 1284), dim3(256), 0, stream,
                       xs, BT1, X, nullptr, b11, nullptr, nullptr, nullptr, nullptr, 512);
    hipLaunchKernelGGL((gemm_k<EPI_BIAS, 512>), dim3(1, 1284), dim3(256), 0, stream,
                       X, BT2, h1, nullptr, b12, nullptr, nullptr, nullptr, nullptr, 128);
    hipLaunchKernelGGL((gemm_k<EPI_GELU, 128>), dim3(4, 1284), dim3(256), 0, stream,
                       h1, BT3, X, nullptr, b21, nullptr, nullptr, nullptr, nullptr, 512);
    hipLaunchKernelGGL((gemm_k<EPI_SEA, 512>), dim3(1, 1284), dim3(256), 0, stream,
                       X, BT4, Afin, nullptr, b22, nullptr, nullptr, nullptr, nullptr, 0);
    hipLaunchKernelGGL((gemm_k<EPI_FINAL, 1024>), dim3(3, 321), dim3(256), 0, stream,
                       Afin, BT5, nullptr, out, btr, bse, rvw, rvb, stats, 0);
}

// Round 2
// 577.743 us; speedup vs baseline: 1.0811x; 1.0811x over previous
//
#include <hip/hip_runtime.h>
#include <math.h>

// Problem constants
#define BB   128
#define LL   512
#define CC   321
#define PREDD 336
// Seasonal MLP: rows = B*C*S = 164352, dims 128 -> 512 -> 128 (x2 blocks)

using bf16x8  = __attribute__((ext_vector_type(8))) __bf16;
using floatx4 = __attribute__((ext_vector_type(4))) float;
using uintx4  = __attribute__((ext_vector_type(4))) unsigned int;
typedef unsigned short u16;

__device__ __forceinline__ u16 f2bf(float f){
    union { float f; unsigned u; } v; v.f = f;
    unsigned r = v.u + 0x7FFFu + ((v.u >> 16) & 1u);   // RNE
    return (u16)(r >> 16);
}

// ---------------- weight prep: fp32 -> bf16, pre-transposed [Ncols][K] ----------------
__global__ void prep_k(const float* __restrict__ W11, const float* __restrict__ W12,
                       const float* __restrict__ W21, const float* __restrict__ W22,
                       const float* __restrict__ Wtr, const float* __restrict__ Wse,
                       u16* __restrict__ BT1, u16* __restrict__ BT2,
                       u16* __restrict__ BT3, u16* __restrict__ BT4,
                       u16* __restrict__ BT5)
{
    int idx = blockIdx.x * 256 + threadIdx.x;
    if (idx < 65536){
        int h = idx >> 7, k = idx & 127;          // BT1/BT3: [512][128] = W11^T / W21^T
        BT1[idx] = f2bf(W11[k*512 + h]);
        BT3[idx] = f2bf(W21[k*512 + h]);
        int n = idx >> 9, k2 = idx & 511;         // BT2/BT4: [128][512] = W12^T / W22^T
        BT2[idx] = f2bf(W12[k2*128 + n]);
        BT4[idx] = f2bf(W22[k2*128 + n]);
    }
    if (idx < 393216){
        // BT5: [384][1024]; k<512 -> W_tr rows; k>=512 -> W_se rows permuted to (s,n)-major
        int p = idx >> 10, k = idx & 1023;
        float v = 0.f;
        if (p < PREDD){
            if (k < 512) v = Wtr[k*PREDD + p];
            else { int kk = k - 512; int s = kk >> 7; int n = kk & 127; v = Wse[(4*n + s)*PREDD + p]; }
        }
        BT5[idx] = f2bf(v);
    }
}

// ---------------- fused RevIN stats + moving-avg decomposition ----------------
// grid: B * ceil(C/16) blocks of 256. Per block: 16 channels, all 512 timesteps in LDS.
// Moving-average commutes with the RevIN affine, so we decompose raw x:
//   trend = (avg25(x) - m)*istd*w + b ;  seasonal = (x - avg25(x))*istd*w
// x tile index: idx(t,c) = t*16 + (t>>5)*2 + c  -- the (t>>5)*2 pad makes every
// access pattern in this kernel <=2-way bank-aliased (free on gfx950, m136).
#define XT(t,c) xt[((t)<<4) + (((t)>>5)<<1) + (c)]
__global__ __launch_bounds__(256) void decomp_k(
    const float* __restrict__ x, const float* __restrict__ rw, const float* __restrict__ rb,
    u16* __restrict__ Afin, u16* __restrict__ xs, float2* __restrict__ stats)
{
    __shared__ float xt[8240];
    __shared__ float red[2][16][16];
    __shared__ float sh_m[16], sh_istd[16];
    int b = blockIdx.x / 21, ct = blockIdx.x % 21;
    int tid = threadIdx.x;

    // ---- phase 1: cooperative load + mean/var stats ----
    int cl = tid & 15, lp = tid >> 4;            // channel-in-tile, t-partition
    int c = ct*16 + cl;
    bool valid = c < CC;
    const float* xb = x + (size_t)b*LL*CC;
    float s = 0.f, q = 0.f;
    for (int i = 0; i < 32; ++i){                // coalesced: 16 consecutive c per quarter-wave
        int t = lp + 16*i;
        float v = valid ? xb[(size_t)t*CC + c] : 0.f;
        XT(t, cl) = v;
        s += v; q += v*v;
    }
    red[0][lp][cl] = s; red[1][lp][cl] = q;
    __syncthreads();
    if (tid < 16){
        float ss = 0.f, qq = 0.f;
        for (int j = 0; j < 16; ++j){ ss += red[0][j][tid]; qq += red[1][j][tid]; }
        float m  = ss * (1.f/512.f);
        float var = qq * (1.f/512.f) - m*m;
        float sd = sqrtf(var + 1e-5f);
        sh_m[tid] = m; sh_istd[tid] = 1.f/sd;
        int cc = ct*16 + tid;
        if (cc < CC) stats[(size_t)b*CC + cc] = make_float2(m, sd);
    }
    __syncthreads();

    // ---- phase 2: sliding 25-tap window; register-buffered 16B stores ----
    // lanes 16k..16k+15 of a wave cover 16 t-chunks of ONE channel -> each
    // thread's outputs are contiguous 16B runs inside a contiguous 1KB row.
    int ch = tid >> 4, tp = tid & 15;
    int c2 = ct*16 + ch;
    if (c2 >= CC) return;
    float m = sh_m[ch], istd = sh_istd[ch];
    float w = rw[c2] * istd, bbv = rb[c2];
    size_t bc = (size_t)b*CC + c2;
    u16* tr  = Afin + bc*1024;                   // trend -> concat-A cols [0,512), 1KB/row
    u16* xsr = xs   + bc*512;                    // seasonal split layout: rows 4bc..4bc+3 contiguous
    int t0 = tp*32;

    float win = 0.f;                             // 25-tap replicate-clamped window sum
#pragma unroll
    for (int d = -12; d <= 12; ++d){
        int u = t0 + d; u = u < 0 ? 0 : (u > 511 ? 511 : u);
        win += XT(u, ch);
    }
    u16 trbuf[8];
    u16 xsbuf[4][8];                             // [s][n-chunk], each row -> one 16B store
#pragma unroll
    for (int i = 0; i < 32; ++i){
        int t = t0 + i;
        float Ax = win * (1.f/25.f);
        float xv = XT(t, ch);
        trbuf[i & 7] = f2bf((Ax - m)*w + bbv);
        xsbuf[i & 3][i >> 2] = f2bf((xv - Ax)*w);
        if ((i & 7) == 7)
            *(uintx4*)(tr + t0 + (i & ~7)) = *(const uintx4*)trbuf;
        int uo = t - 12; uo = uo < 0 ? 0 : uo;   // slide window t -> t+1
        int un = t + 13; un = un > 511 ? 511 : un;
        win += XT(un, ch) - XT(uo, ch);
    }
#pragma unroll
    for (int s4 = 0; s4 < 4; ++s4)
        *(uintx4*)(xsr + s4*128 + tp*8) = *(const uintx4*)xsbuf[s4];
}

// ---------------- bf16 MFMA GEMM, 128x128 tile, fused epilogues ----------------
enum { EPI_GELU = 0, EPI_BIAS = 1, EPI_SEA = 2, EPI_FINAL = 3 };

template<int EPI, int KDIM>
__global__ __launch_bounds__(256, 2) void gemm_k(
    const u16* __restrict__ A, const u16* __restrict__ BT,
    u16* __restrict__ Cb, float* __restrict__ Cf,
    const float* __restrict__ bias, const float* __restrict__ bias2,
    const float* __restrict__ rw, const float* __restrict__ rb,
    const float2* __restrict__ stats, int Ncols)
{
    __shared__ u16 lA[128*72];   // stride 72 bf16: 16B-aligned rows, conflict-free frag reads
    __shared__ u16 lB[128*72];
    const int tid = threadIdx.x;
    const int row0 = blockIdx.y * 128;
    const int col0 = blockIdx.x * 128;
    const int lane = tid & 63;
    const int wv = tid >> 6;
    const int wm = wv & 1, wn = wv >> 1;         // 2x2 wave grid, 64x64 per wave
    const int quad = lane >> 4, cl = lane & 15;

    floatx4 acc[16];
#pragma unroll
    for (int i = 0; i < 16; ++i) acc[i] = (floatx4){0.f,0.f,0.f,0.f};

    const int srow = tid >> 3, sseg = tid & 7;   // staging: 8 threads x 16B per row
    const u16* Ag = A  + (size_t)(row0 + srow)*KDIM + sseg*8;
    const u16* Bg = BT + (size_t)(col0 + srow)*KDIM + sseg*8;

    for (int k0 = 0; k0 < KDIM; k0 += 64){
#pragma unroll
        for (int p = 0; p < 4; ++p){
            uintx4 av = *(const uintx4*)(Ag + (size_t)p*32*KDIM + k0);
            uintx4 bv = *(const uintx4*)(Bg + (size_t)p*32*KDIM + k0);
            int r = p*32 + srow;
            *(uintx4*)(lA + r*72 + sseg*8) = av;
            *(uintx4*)(lB + r*72 + sseg*8) = bv;
        }
        __syncthreads();
#pragma unroll
        for (int kk = 0; kk < 2; ++kk){
            const int lk = kk*32 + quad*8;
            bf16x8 af[4], bfr[4];
#pragma unroll
            for (int mt = 0; mt < 4; ++mt) af[mt]  = *(const bf16x8*)(lA + (wm*64 + mt*16 + cl)*72 + lk);
#pragma unroll
            for (int nt = 0; nt < 4; ++nt) bfr[nt] = *(const bf16x8*)(lB + (wn*64 + nt*16 + cl)*72 + lk);
#pragma unroll
            for (int mt = 0; mt < 4; ++mt)
#pragma unroll
                for (int nt = 0; nt < 4; ++nt)
                    acc[mt*4+nt] = __builtin_amdgcn_mfma_f32_16x16x32_bf16(af[mt], bfr[nt], acc[mt*4+nt], 0, 0, 0);
        }
        __syncthreads();
    }

#pragma unroll
    for (int mt = 0; mt < 4; ++mt){
#pragma unroll
        for (int nt = 0; nt < 4; ++nt){
            floatx4 v = acc[mt*4+nt];
            int gc = col0 + wn*64 + nt*16 + cl;
#pragma unroll
            for (int i = 0; i < 4; ++i){
                int gr = row0 + wm*64 + mt*16 + quad*4 + i;
                float val = v[i];
                if (EPI == EPI_GELU){
                    val += bias[gc];
                    val = 0.5f*val*(1.f + erff(val*0.70710678118654752f));   // exact gelu
                    Cb[(size_t)gr*Ncols + gc] = f2bf(val);
                } else if (EPI == EPI_BIAS){
                    val += bias[gc];
                    Cb[(size_t)gr*Ncols + gc] = f2bf(val);
                } else if (EPI == EPI_SEA){
                    // h2 row (bc*4+s, n) -> concat-A[bc][512 + s*128 + n]
                    val += bias[gc];
                    Cb[(size_t)(gr>>2)*1024 + 512 + (size_t)(gr&3)*128 + gc] = f2bf(val);
                } else { // EPI_FINAL: biases + RevIN denorm + [B,PRED,C] transpose
                    if (gc < PREDD){
                        val += bias[gc] + bias2[gc];
                        int bv2 = gr / CC;
                        int c  = gr - bv2*CC;
                        val = (val - rb[c]) / (rw[c] + 1e-10f);
                        float2 st = stats[gr];
                        val = val*st.y + st.x;
                        Cf[(size_t)bv2*(PREDD*CC) + (size_t)gc*CC + c] = val;
                    }
                }
            }
        }
    }
}

extern "C" void kernel_launch(void* const* d_in, const int* in_sizes, int n_in,
                              void* d_out, int out_size, void* d_ws, size_t ws_size,
                              hipStream_t stream)
{
    const float* x   = (const float*)d_in[0];
    const float* rvw = (const float*)d_in[1];
    const float* rvb = (const float*)d_in[2];
    const float* W11 = (const float*)d_in[3];
    const float* b11 = (const float*)d_in[4];
    const float* W12 = (const float*)d_in[5];
    const float* b12 = (const float*)d_in[6];
    const float* W21 = (const float*)d_in[7];
    const float* b21 = (const float*)d_in[8];
    const float* W22 = (const float*)d_in[9];
    const float* b22 = (const float*)d_in[10];
    const float* Wtr = (const float*)d_in[11];
    const float* btr = (const float*)d_in[12];
    const float* Wse = (const float*)d_in[13];
    const float* bse = (const float*)d_in[14];
    float* out = (float*)d_out;

    // workspace layout (bytes), all offsets 256-aligned; total ~296 MB
    char* ws = (char*)d_ws;
    u16* BT1 = (u16*)(ws + 0);            //  512x128 bf16
    u16* BT2 = (u16*)(ws + 131072);       //  128x512
    u16* BT3 = (u16*)(ws + 262144);       //  512x128
    u16* BT4 = (u16*)(ws + 393216);       //  128x512
    u16* BT5 = (u16*)(ws + 524288);       //  384x1024
    float2* stats = (float2*)(ws + 1310720);      // 41088 x {mean,std}
    u16* Afin = (u16*)(ws + 1639424);     // concat-A [41088][1024]: trend | sea
    u16* xs   = (u16*)(ws + 85787648);    // [164352][128] split seasonal (reused as h1)
    u16* X    = (u16*)(ws + 127861760);   // [164352][512] MLP hidden
    u16* h1   = xs;

    hipLaunchKernelGGL(prep_k, dim3(1536), dim3(256), 0, stream,
                       W11, W12, W21, W22, Wtr, Wse, BT1, BT2, BT3, BT4, BT5);
    hipLaunchKernelGGL(decomp_k, dim3(128*21), dim3(256), 0, stream,
                       x, rvw, rvb, Afin, xs, stats);
    hipLaunchKernelGGL((gemm_k<EPI_GELU, 128>), dim3(4, 1284), dim3(256), 0, stream,
                       xs, BT1, X, nullptr, b11, nullptr, nullptr, nullptr, nullptr, 512);
    hipLaunchKernelGGL((gemm_k<EPI_BIAS, 512>), dim3(1, 1284), dim3(256), 0, stream,
                       X, BT2, h1, nullptr, b12, nullptr, nullptr, nullptr, nullptr, 128);
    hipLaunchKernelGGL((gemm_k<EPI_GELU, 128>), dim3(4, 1284), dim3(256), 0, stream,
                       h1, BT3, X, nullptr, b21, nullptr, nullptr, nullptr, nullptr, 512);
    hipLaunchKernelGGL((gemm_k<EPI_SEA, 512>), dim3(1, 1284), dim3(256), 0, stream,
                       X, BT4, Afin, nullptr, b22, nullptr, nullptr, nullptr, nullptr, 0);
    hipLaunchKernelGGL((gemm_k<EPI_FINAL, 1024>), dim3(3, 321), dim3(256), 0, stream,
                       Afin, BT5, nullptr, out, btr, bse, rvw, rvb, stats, 0);
}

// Round 4
// 523.079 us; speedup vs baseline: 1.1940x; 1.1045x over previous
//
#include <hip/hip_runtime.h>
#include <math.h>

// Problem constants
#define BB   128
#define LL   512
#define CC   321
#define PREDD 336
// Seasonal MLP: rows = B*C*S = 164352, dims 128 -> 512 -> 128 (x2 blocks)

using bf16x8  = __attribute__((ext_vector_type(8))) __bf16;
using floatx4 = __attribute__((ext_vector_type(4))) float;
using uintx4  = __attribute__((ext_vector_type(4))) unsigned int;
typedef unsigned short u16;

__device__ __forceinline__ u16 f2bf(float f){
    union { float f; unsigned u; } v; v.f = f;
    unsigned r = v.u + 0x7FFFu + ((v.u >> 16) & 1u);   // RNE
    return (u16)(r >> 16);
}

// tanh-GELU: 0.5x(1+tanh(sqrt(2/pi)(x+0.044715x^3))) = x*t/(1+t), t=exp(2u).
// Max |err| vs exact erf-GELU ~3e-4, far below bf16 rounding of the hidden.
__device__ __forceinline__ float fgelu(float x){
    float u = x*(0.7978845608f + 0.035677408f*x*x);
    float a = fminf(u*2.8853900818f, 80.f);       // 2*log2(e)*u, clamp vs inf/inf
    float t = __builtin_amdgcn_exp2f(a);          // v_exp_f32
    return x*t*__builtin_amdgcn_rcpf(1.f + t);
}

// ---------------- weight prep: fp32 -> bf16, pre-transposed [Ncols][K] ----------------
__global__ void prep_k(const float* __restrict__ W11, const float* __restrict__ W12,
                       const float* __restrict__ W21, const float* __restrict__ W22,
                       const float* __restrict__ Wtr, const float* __restrict__ Wse,
                       u16* __restrict__ BT1, u16* __restrict__ BT2,
                       u16* __restrict__ BT3, u16* __restrict__ BT4,
                       u16* __restrict__ BT5)
{
    int idx = blockIdx.x * 256 + threadIdx.x;
    if (idx < 65536){
        int h = idx >> 7, k = idx & 127;          // BT1/BT3: [512][128] = W11^T / W21^T
        BT1[idx] = f2bf(W11[k*512 + h]);
        BT3[idx] = f2bf(W21[k*512 + h]);
        int n = idx >> 9, k2 = idx & 511;         // BT2/BT4: [128][512] = W12^T / W22^T
        BT2[idx] = f2bf(W12[k2*128 + n]);
        BT4[idx] = f2bf(W22[k2*128 + n]);
    }
    if (idx < 393216){
        // BT5: [384][1024]; k<512 -> W_tr rows; k>=512 -> W_se rows permuted to (s,n)-major
        int p = idx >> 10, k = idx & 1023;
        float v = 0.f;
        if (p < PREDD){
            if (k < 512) v = Wtr[k*PREDD + p];
            else { int kk = k - 512; int s = kk >> 7; int n = kk & 127; v = Wse[(4*n + s)*PREDD + p]; }
        }
        BT5[idx] = f2bf(v);
    }
}

// ---------------- fused RevIN stats + moving-avg decomposition ----------------
#define XT(t,c) xt[((t)<<4) + (((t)>>5)<<1) + (c)]
__global__ __launch_bounds__(256) void decomp_k(
    const float* __restrict__ x, const float* __restrict__ rw, const float* __restrict__ rb,
    u16* __restrict__ Afin, u16* __restrict__ xs, float2* __restrict__ stats)
{
    __shared__ float xt[8240];
    __shared__ float red[2][16][16];
    __shared__ float sh_m[16], sh_istd[16];
    int b = blockIdx.x / 21, ct = blockIdx.x % 21;
    int tid = threadIdx.x;

    int cl = tid & 15, lp = tid >> 4;
    int c = ct*16 + cl;
    bool valid = c < CC;
    const float* xb = x + (size_t)b*LL*CC;
    float s = 0.f, q = 0.f;
    for (int i = 0; i < 32; ++i){
        int t = lp + 16*i;
        float v = valid ? xb[(size_t)t*CC + c] : 0.f;
        XT(t, cl) = v;
        s += v; q += v*v;
    }
    red[0][lp][cl] = s; red[1][lp][cl] = q;
    __syncthreads();
    if (tid < 16){
        float ss = 0.f, qq = 0.f;
        for (int j = 0; j < 16; ++j){ ss += red[0][j][tid]; qq += red[1][j][tid]; }
        float m  = ss * (1.f/512.f);
        float var = qq * (1.f/512.f) - m*m;
        float sd = sqrtf(var + 1e-5f);
        sh_m[tid] = m; sh_istd[tid] = 1.f/sd;
        int cc = ct*16 + tid;
        if (cc < CC) stats[(size_t)b*CC + cc] = make_float2(m, sd);
    }
    __syncthreads();

    int ch = tid >> 4, tp = tid & 15;
    int c2 = ct*16 + ch;
    if (c2 >= CC) return;
    float m = sh_m[ch], istd = sh_istd[ch];
    float w = rw[c2] * istd, bbv = rb[c2];
    size_t bc = (size_t)b*CC + c2;
    u16* tr  = Afin + bc*1024;
    u16* xsr = xs   + bc*512;
    int t0 = tp*32;

    float win = 0.f;
#pragma unroll
    for (int d = -12; d <= 12; ++d){
        int u = t0 + d; u = u < 0 ? 0 : (u > 511 ? 511 : u);
        win += XT(u, ch);
    }
    u16 trbuf[8];
    u16 xsbuf[4][8];
#pragma unroll
    for (int i = 0; i < 32; ++i){
        int t = t0 + i;
        float Ax = win * (1.f/25.f);
        float xv = XT(t, ch);
        trbuf[i & 7] = f2bf((Ax - m)*w + bbv);
        xsbuf[i & 3][i >> 2] = f2bf((xv - Ax)*w);
        if ((i & 7) == 7)
            *(uintx4*)(tr + t0 + (i & ~7)) = *(const uintx4*)trbuf;
        int uo = t - 12; uo = uo < 0 ? 0 : uo;
        int un = t + 13; un = un > 511 ? 511 : un;
        win += XT(un, ch) - XT(uo, ch);
    }
#pragma unroll
    for (int s4 = 0; s4 < 4; ++s4)
        *(uintx4*)(xsr + s4*128 + tp*8) = *(const uintx4*)xsbuf[s4];
}

// ---------------- fully fused 2-block MLP: xs -> h1 -> h2 -> Afin[:,512:] ----------------
// Per block: 128 rows. A-frags cached in registers (reused over 8 hidden chunks).
// Hidden chunk = 64: Hc = A x W1c (K=128), GELU, LDS round-trip (C->A layout),
// Y += Hc x W2c (K=64). h1 tile lives in LDS between MLP blocks.
#define SA 136                    // u16 stride for [.][128] k-major tiles
#define SB 72                     // u16 stride for [.][64] k-major tiles
#define HB0 8704                  // Hbuf offset (u16): after Wbuf 64*136
#define W2B0 17920                // W2buf offset (u16): after Hbuf 128*72
__global__ __launch_bounds__(256, 2) void mlp_fused_k(
    const u16* __restrict__ xs,
    const u16* __restrict__ BT1, const float* __restrict__ b11,
    const u16* __restrict__ BT2, const float* __restrict__ b12,
    const u16* __restrict__ BT3, const float* __restrict__ b21,
    const u16* __restrict__ BT4, const float* __restrict__ b22,
    u16* __restrict__ Afin)
{
    __shared__ u16 lds[27136];    // 54.3 KB: Abuf(0..17408) overlays Wbuf+Hbuf; W2buf separate
    const int tid = threadIdx.x;
    const int row0 = blockIdx.x * 128;
    const int lane = tid & 63;
    const int wv = tid >> 6;
    const int wm = wv & 1, wn = wv >> 1;          // 2x2 wave grid
    const int quad = lane >> 4, cl = lane & 15;

    // stage xs tile [128][128] -> lds[0..], stride SA
    {
        int r = tid >> 4, c8 = (tid & 15) * 8;
        const u16* src = xs + (size_t)(row0 + r)*128 + c8;
        u16* dst = lds + r*SA + c8;
#pragma unroll
        for (int p = 0; p < 8; ++p)
            *(uintx4*)(dst + p*16*SA) = *(const uintx4*)(src + (size_t)p*16*128);
    }
    __syncthreads();

    for (int mlp = 0; mlp < 2; ++mlp){
        const u16*  BTa = mlp ? BT3 : BT1;        // [512][128] hidden-major
        const float* ba = mlp ? b21 : b11;
        const u16*  BTb = mlp ? BT4 : BT2;        // [128][512] n-major
        const float* bb = mlp ? b22 : b12;

        // cache A fragments: rows wm*64.., full K=128
        bf16x8 afrag[4][4];
#pragma unroll
        for (int mt = 0; mt < 4; ++mt)
#pragma unroll
            for (int ks = 0; ks < 4; ++ks)
                afrag[mt][ks] = *(const bf16x8*)(lds + (wm*64 + mt*16 + cl)*SA + ks*32 + quad*8);
        __syncthreads();                          // afrag reads before Wbuf staging overwrites

        floatx4 Yacc[16];
#pragma unroll
        for (int i = 0; i < 16; ++i) Yacc[i] = (floatx4){0.f,0.f,0.f,0.f};

        for (int hc = 0; hc < 8; ++hc){
            // stage W1 chunk [64 hidden][128 k] -> Wbuf (lds[0..], stride SA)
            {
                int r = tid >> 4, c8 = (tid & 15) * 8;
                const u16* src = BTa + (size_t)(hc*64 + r)*128 + c8;
                u16* dst = lds + r*SA + c8;
#pragma unroll
                for (int p = 0; p < 4; ++p)
                    *(uintx4*)(dst + p*16*SA) = *(const uintx4*)(src + (size_t)p*16*128);
            }
            __syncthreads();

            // Hc = A x W1c : [128 rows][64 hidden], waves: wm=row-half, wn=col-half(32)
            floatx4 hacc[8];
#pragma unroll
            for (int i = 0; i < 8; ++i) hacc[i] = (floatx4){0.f,0.f,0.f,0.f};
#pragma unroll
            for (int ks = 0; ks < 4; ++ks){
                bf16x8 bfr0 = *(const bf16x8*)(lds + (wn*32 +  0 + cl)*SA + ks*32 + quad*8);
                bf16x8 bfr1 = *(const bf16x8*)(lds + (wn*32 + 16 + cl)*SA + ks*32 + quad*8);
#pragma unroll
                for (int mt = 0; mt < 4; ++mt){
                    hacc[mt*2+0] = __builtin_amdgcn_mfma_f32_16x16x32_bf16(afrag[mt][ks], bfr0, hacc[mt*2+0], 0, 0, 0);
                    hacc[mt*2+1] = __builtin_amdgcn_mfma_f32_16x16x32_bf16(afrag[mt][ks], bfr1, hacc[mt*2+1], 0, 0, 0);
                }
            }
            // GELU + bias -> Hbuf [r][h] stride SB
            {
                int hl0 = wn*32 + cl;
                float bav0 = ba[hc*64 + hl0];
                float bav1 = ba[hc*64 + hl0 + 16];
#pragma unroll
                for (int mt = 0; mt < 4; ++mt){
                    floatx4 v0 = hacc[mt*2+0], v1 = hacc[mt*2+1];
#pragma unroll
                    for (int i = 0; i < 4; ++i){
                        int r = wm*64 + mt*16 + quad*4 + i;
                        lds[HB0 + r*SB + hl0]      = f2bf(fgelu(v0[i] + bav0));
                        lds[HB0 + r*SB + hl0 + 16] = f2bf(fgelu(v1[i] + bav1));
                    }
                }
            }
            // stage W2 chunk [128 n][64 k] -> W2buf stride SB
            {
                int r = tid >> 3, c8 = (tid & 7) * 8;
                const u16* src = BTb + (size_t)r*512 + hc*64 + c8;
                u16* dst = lds + W2B0 + r*SB + c8;
#pragma unroll
                for (int p = 0; p < 4; ++p)
                    *(uintx4*)(dst + p*32*SB) = *(const uintx4*)(src + (size_t)p*32*512);
            }
            __syncthreads();

            // Y += Hc x W2c : K=64, waves 2x2 over [128][128]
#pragma unroll
            for (int ks = 0; ks < 2; ++ks){
                bf16x8 a2[4], b2[4];
#pragma unroll
                for (int mt = 0; mt < 4; ++mt) a2[mt] = *(const bf16x8*)(lds + HB0  + (wm*64 + mt*16 + cl)*SB + ks*32 + quad*8);
#pragma unroll
                for (int nt = 0; nt < 4; ++nt) b2[nt] = *(const bf16x8*)(lds + W2B0 + (wn*64 + nt*16 + cl)*SB + ks*32 + quad*8);
#pragma unroll
                for (int mt = 0; mt < 4; ++mt)
#pragma unroll
                    for (int nt = 0; nt < 4; ++nt)
                        Yacc[mt*4+nt] = __builtin_amdgcn_mfma_f32_16x16x32_bf16(a2[mt], b2[nt], Yacc[mt*4+nt], 0, 0, 0);
            }
        }
        __syncthreads();                          // Y-phase LDS reads done

        if (mlp == 0){
            // h1 = Y + b12 -> bf16 -> Abuf (lds[0..], stride SA)
#pragma unroll
            for (int mt = 0; mt < 4; ++mt)
#pragma unroll
                for (int nt = 0; nt < 4; ++nt){
                    int c = wn*64 + nt*16 + cl;
                    float bv = bb[c];
                    floatx4 v = Yacc[mt*4+nt];
#pragma unroll
                    for (int i = 0; i < 4; ++i){
                        int r = wm*64 + mt*16 + quad*4 + i;
                        lds[r*SA + c] = f2bf(v[i] + bv);
                    }
                }
            __syncthreads();                      // h1 complete before mlp=1 afrag reads
        } else {
            // h2 + b22 -> Afin[:, 512 + s*128 + n]  (row gr = bc*4+s)
#pragma unroll
            for (int mt = 0; mt < 4; ++mt)
#pragma unroll
                for (int nt = 0; nt < 4; ++nt){
                    int c = wn*64 + nt*16 + cl;
                    float bv = bb[c];
                    floatx4 v = Yacc[mt*4+nt];
#pragma unroll
                    for (int i = 0; i < 4; ++i){
                        int gr = row0 + wm*64 + mt*16 + quad*4 + i;
                        Afin[(size_t)(gr>>2)*1024 + 512 + (size_t)(gr&3)*128 + c] = f2bf(v[i] + bv);
                    }
                }
        }
    }
}

// ---------------- final fused-head GEMM: [41088][1024] x [384][1024]^T ----------------
__global__ __launch_bounds__(256, 2) void head_gemm_k(
    const u16* __restrict__ A, const u16* __restrict__ BT,
    float* __restrict__ Cf,
    const float* __restrict__ bias, const float* __restrict__ bias2,
    const float* __restrict__ rw, const float* __restrict__ rb,
    const float2* __restrict__ stats)
{
    __shared__ u16 lA[128*72];
    __shared__ u16 lB[128*72];
    const int tid = threadIdx.x;
    const int row0 = blockIdx.y * 128;
    const int col0 = blockIdx.x * 128;
    const int lane = tid & 63;
    const int wv = tid >> 6;
    const int wm = wv & 1, wn = wv >> 1;
    const int quad = lane >> 4, cl = lane & 15;

    floatx4 acc[16];
#pragma unroll
    for (int i = 0; i < 16; ++i) acc[i] = (floatx4){0.f,0.f,0.f,0.f};

    const int srow = tid >> 3, sseg = tid & 7;
    const u16* Ag = A  + (size_t)(row0 + srow)*1024 + sseg*8;
    const u16* Bg = BT + (size_t)(col0 + srow)*1024 + sseg*8;

    for (int k0 = 0; k0 < 1024; k0 += 64){
#pragma unroll
        for (int p = 0; p < 4; ++p){
            uintx4 av = *(const uintx4*)(Ag + (size_t)p*32*1024 + k0);
            uintx4 bv = *(const uintx4*)(Bg + (size_t)p*32*1024 + k0);
            int r = p*32 + srow;
            *(uintx4*)(lA + r*72 + sseg*8) = av;
            *(uintx4*)(lB + r*72 + sseg*8) = bv;
        }
        __syncthreads();
#pragma unroll
        for (int kk = 0; kk < 2; ++kk){
            const int lk = kk*32 + quad*8;
            bf16x8 af[4], bfr[4];
#pragma unroll
            for (int mt = 0; mt < 4; ++mt) af[mt]  = *(const bf16x8*)(lA + (wm*64 + mt*16 + cl)*72 + lk);
#pragma unroll
            for (int nt = 0; nt < 4; ++nt) bfr[nt] = *(const bf16x8*)(lB + (wn*64 + nt*16 + cl)*72 + lk);
#pragma unroll
            for (int mt = 0; mt < 4; ++mt)
#pragma unroll
                for (int nt = 0; nt < 4; ++nt)
                    acc[mt*4+nt] = __builtin_amdgcn_mfma_f32_16x16x32_bf16(af[mt], bfr[nt], acc[mt*4+nt], 0, 0, 0);
        }
        __syncthreads();
    }

#pragma unroll
    for (int mt = 0; mt < 4; ++mt)
#pragma unroll
        for (int nt = 0; nt < 4; ++nt){
            floatx4 v = acc[mt*4+nt];
            int gc = col0 + wn*64 + nt*16 + cl;
            if (gc >= PREDD) continue;
            float bsum = bias[gc] + bias2[gc];
#pragma unroll
            for (int i = 0; i < 4; ++i){
                int gr = row0 + wm*64 + mt*16 + quad*4 + i;
                float val = v[i] + bsum;
                int bv2 = gr / CC;
                int c  = gr - bv2*CC;
                val = (val - rb[c]) / (rw[c] + 1e-10f);
                float2 st = stats[gr];
                val = val*st.y + st.x;
                Cf[(size_t)bv2*(PREDD*CC) + (size_t)gc*CC + c] = val;
            }
        }
}

extern "C" void kernel_launch(void* const* d_in, const int* in_sizes, int n_in,
                              void* d_out, int out_size, void* d_ws, size_t ws_size,
                              hipStream_t stream)
{
    const float* x   = (const float*)d_in[0];
    const float* rvw = (const float*)d_in[1];
    const float* rvb = (const float*)d_in[2];
    const float* W11 = (const float*)d_in[3];
    const float* b11 = (const float*)d_in[4];
    const float* W12 = (const float*)d_in[5];
    const float* b12 = (const float*)d_in[6];
    const float* W21 = (const float*)d_in[7];
    const float* b21 = (const float*)d_in[8];
    const float* W22 = (const float*)d_in[9];
    const float* b22 = (const float*)d_in[10];
    const float* Wtr = (const float*)d_in[11];
    const float* btr = (const float*)d_in[12];
    const float* Wse = (const float*)d_in[13];
    const float* bse = (const float*)d_in[14];
    float* out = (float*)d_out;

    char* ws = (char*)d_ws;
    u16* BT1 = (u16*)(ws + 0);            //  512x128 bf16
    u16* BT2 = (u16*)(ws + 131072);       //  128x512
    u16* BT3 = (u16*)(ws + 262144);       //  512x128
    u16* BT4 = (u16*)(ws + 393216);       //  128x512
    u16* BT5 = (u16*)(ws + 524288);       //  384x1024
    float2* stats = (float2*)(ws + 1310720);      // 41088 x {mean,std}
    u16* Afin = (u16*)(ws + 1639424);     // concat-A [41088][1024]: trend | sea
    u16* xs   = (u16*)(ws + 85787648);    // [164352][128] split seasonal

    hipLaunchKernelGGL(prep_k, dim3(1536), dim3(256), 0, stream,
                       W11, W12, W21, W22, Wtr, Wse, BT1, BT2, BT3, BT4, BT5);
    hipLaunchKernelGGL(decomp_k, dim3(128*21), dim3(256), 0, stream,
                       x, rvw, rvb, Afin, xs, stats);
    hipLaunchKernelGGL(mlp_fused_k, dim3(1284), dim3(256), 0, stream,
                       xs, BT1, b11, BT2, b12, BT3, b21, BT4, b22, Afin);
    hipLaunchKernelGGL(head_gemm_k, dim3(3, 321), dim3(256), 0, stream,
                       Afin, BT5, out, btr, bse, rvw, rvb, stats);
}